// Round 5
// baseline (579.892 us; speedup 1.0000x reference)
//
#include <hip/hip_runtime.h>
#include <hip/hip_bf16.h>
#include <stdint.h>

#define DMODEL 1024
#define NEXP   8
#define HSZ    4096
#define NTOK   4096   // B*S
#define KSPLIT 2      // gemm2 split-K factor

typedef __attribute__((ext_vector_type(8))) short bf16x8;
typedef __attribute__((ext_vector_type(4))) float f32x4;

// fp32 -> bf16 round-to-nearest
__device__ __forceinline__ unsigned short f2bf(float f) {
  union { float f; unsigned u; } v; v.f = f;
  return (unsigned short)((v.u + 0x8000u) >> 16);
}

// async 16B/lane global->LDS DMA. Per-lane global addr; LDS dest wave-uniform,
// HW scatters lane l -> lds + l*16.
__device__ __forceinline__ void gl2lds16(const void* g, void* lds) {
  __builtin_amdgcn_global_load_lds(
      (const __attribute__((address_space(1))) unsigned*)g,
      (__attribute__((address_space(3))) unsigned*)lds, 16, 0, 0);
}

// ---------------- fused fp32 -> bf16 bulk convert (w1, w2) -----------------
__global__ __launch_bounds__(256) void cvt_all_kernel(
    const float* __restrict__ w1, const float* __restrict__ w2,
    unsigned short* __restrict__ w1b, unsigned short* __restrict__ w2b) {
  const size_t n1 = (size_t)NEXP * HSZ * DMODEL / 4;
  size_t i = (size_t)blockIdx.x * 256 + threadIdx.x;
  const float* src; unsigned short* dst; size_t j;
  if (i < n1) { src = w1; dst = w1b; j = i; }
  else        { src = w2; dst = w2b; j = i - n1; }
  float4 v = ((const float4*)src)[j];
  ((ushort4*)dst)[j] = make_ushort4(f2bf(v.x), f2bf(v.y), f2bf(v.z), f2bf(v.w));
}

// ---------------- router: 256 blocks x 16 tokens, batched atomics ----------
__global__ __launch_bounds__(256) void router_kernel(
    const float* __restrict__ x, const float* __restrict__ gw,
    int* __restrict__ cnt, int* __restrict__ tokl, float* __restrict__ twgt,
    int* __restrict__ sidx, unsigned short* __restrict__ xb) {
  __shared__ int lcnt[NEXP];
  __shared__ int lbase[NEXP];
  __shared__ int rE[32];
  __shared__ int rS[32];
  __shared__ float rW[32];
  const int tid = threadIdx.x;
  const int wave = tid >> 6;
  const int lane = tid & 63;
  if (tid < NEXP) lcnt[tid] = 0;
  __syncthreads();

  for (int i = 0; i < 4; ++i) {
    int lt = wave * 4 + i;
    int t = blockIdx.x * 16 + lt;
    const float* xr = x + (size_t)t * DMODEL;
    unsigned short* xbr = xb + (size_t)t * DMODEL;
    float acc[NEXP];
#pragma unroll
    for (int e = 0; e < NEXP; ++e) acc[e] = 0.f;
    for (int d = lane; d < DMODEL; d += 64) {
      float xv = xr[d];
      xbr[d] = f2bf(xv);
#pragma unroll
      for (int e = 0; e < NEXP; ++e) acc[e] = fmaf(xv, gw[e * DMODEL + d], acc[e]);
    }
#pragma unroll
    for (int e = 0; e < NEXP; ++e) {
#pragma unroll
      for (int o = 32; o > 0; o >>= 1) acc[e] += __shfl_down(acc[e], o);
    }
    if (lane == 0) {
      float m = acc[0];
#pragma unroll
      for (int e = 1; e < NEXP; ++e) m = fmaxf(m, acc[e]);
      float p[NEXP]; float s = 0.f;
#pragma unroll
      for (int e = 0; e < NEXP; ++e) { p[e] = __expf(acc[e] - m); s += p[e]; }
      float inv = 1.f / s;
      int i0 = 0; float b0 = p[0];
#pragma unroll
      for (int e = 1; e < NEXP; ++e) if (p[e] > b0) { b0 = p[e]; i0 = e; }
      int i1 = (i0 == 0) ? 1 : 0; float b1v = p[i1];
#pragma unroll
      for (int e = 0; e < NEXP; ++e) if (e != i0 && p[e] > b1v) { b1v = p[e]; i1 = e; }
      int s0l = atomicAdd(&lcnt[i0], 1);
      rE[lt * 2] = i0; rS[lt * 2] = s0l; rW[lt * 2] = b0 * inv;
      int s1l = atomicAdd(&lcnt[i1], 1);
      rE[lt * 2 + 1] = i1; rS[lt * 2 + 1] = s1l; rW[lt * 2 + 1] = b1v * inv;
    }
  }
  __syncthreads();
  if (tid < NEXP) lbase[tid] = atomicAdd(&cnt[tid], lcnt[tid]);
  __syncthreads();
  if (tid < 32) {
    int e = rE[tid];
    int p = lbase[e] + rS[tid];
    int t = blockIdx.x * 16 + (tid >> 1);
    tokl[e * NTOK + p] = t;
    twgt[e * NTOK + p] = rW[tid];
    sidx[2 * t + (tid & 1)] = (e << 16) | p;
  }
}

// ===================== 256x256 / BK=64 / 8-wave / 8-phase ===================
// (schedule unchanged from R4 -- verified passing; see R4 comments)
// NEW this round: T1 XCD-chunked block swizzle. Chunk = 16 blocks sharing one
// B-panel (same n-block & z). Linear id b -> XCD b%8 (HW round-robin); we
// permute WORK so chunk c = xcd + 8*chunk_local runs wholly on one XCD.
// Per XCD 32 CUs ~= 2 live chunks -> 2MB B-panels resident in 4MB L2 ->
// B1 staging (the 4-phase-slack boundary-vmcnt path) becomes L2-hit.

#define SOFF(buf, mat, half) (((buf) * 4 + (mat) * 2 + (half)) * 8192)

#define STG_A(buf, half, kt) do { if ((kt) < NSTEP) {                         \
    gl2lds16(aP[half][0] + (size_t)(kt) * 64, &SH[SOFF(buf,0,half) + (w*16)*64]);     \
    gl2lds16(aP[half][1] + (size_t)(kt) * 64, &SH[SOFF(buf,0,half) + (w*16+8)*64]); } } while(0)

#define STG_B(buf, half, kt) do { if ((kt) < NSTEP) {                         \
    gl2lds16(bP + (size_t)((half)*128) * Bstr + (size_t)(kt) * 64, &SH[SOFF(buf,1,half) + (w*16)*64]);   \
    gl2lds16(bP + (size_t)((half)*128+8) * Bstr + (size_t)(kt) * 64, &SH[SOFF(buf,1,half) + (w*16+8)*64]); } } while(0)

#define RD_A(dst, buf, half) do {                                             \
    dst[0][0] = *(const bf16x8*)&SH[SOFF(buf,0,half) + aoff[0][0]];           \
    dst[0][1] = *(const bf16x8*)&SH[SOFF(buf,0,half) + aoff[0][1]];           \
    dst[1][0] = *(const bf16x8*)&SH[SOFF(buf,0,half) + aoff[1][0]];           \
    dst[1][1] = *(const bf16x8*)&SH[SOFF(buf,0,half) + aoff[1][1]]; } while(0)

#define RD_B(dst, buf, half) do {                                             \
    _Pragma("unroll") for (int j_ = 0; j_ < 4; ++j_) {                        \
      dst[j_][0] = *(const bf16x8*)&SH[SOFF(buf,1,half) + boff[j_][0]];       \
      dst[j_][1] = *(const bf16x8*)&SH[SOFF(buf,1,half) + boff[j_][1]]; } } while(0)

#define MFMA_Q(q, a, b) do {                                                  \
    _Pragma("unroll") for (int i_ = 0; i_ < 2; ++i_)                          \
    _Pragma("unroll") for (int j_ = 0; j_ < 4; ++j_)                          \
    _Pragma("unroll") for (int k_ = 0; k_ < 2; ++k_)                          \
      acc[q][i_][j_] = __builtin_amdgcn_mfma_f32_16x16x32_bf16(               \
          b[j_][k_], a[i_][k_], acc[q][i_][j_], 0, 0, 0); } while(0)

#define PH_COMPUTE(q, a, b)                                                   \
    __builtin_amdgcn_s_barrier();                                             \
    asm volatile("s_waitcnt lgkmcnt(0)" ::: "memory");                        \
    __builtin_amdgcn_sched_barrier(0);                                        \
    __builtin_amdgcn_s_setprio(1);                                            \
    MFMA_Q(q, a, b);                                                          \
    __builtin_amdgcn_s_setprio(0);                                            \
    __builtin_amdgcn_sched_barrier(0);                                        \
    __builtin_amdgcn_s_barrier();

#define KTILE(buf, t) do {                                                    \
    /* PH0: Q(0,0) */                                                         \
    RD_A(a0f, buf, 0); RD_B(b0f, buf, 0);                                     \
    STG_B(buf ^ 1, 1, (t) + 1);                                               \
    PH_COMPUTE(0, a0f, b0f)                                                   \
    /* PH1: Q(0,1) */                                                         \
    RD_B(b1f, buf, 1);                                                        \
    STG_A(buf, 0, (t) + 2);                                                   \
    PH_COMPUTE(1, a0f, b1f)                                                   \
    /* PH2: Q(1,0) */                                                         \
    RD_A(a1f, buf, 1);                                                        \
    STG_B(buf, 0, (t) + 2);                                                   \
    PH_COMPUTE(2, a1f, b0f)                                                   \
    /* PH3: Q(1,1) + boundary vmcnt */                                        \
    STG_A(buf, 1, (t) + 2);                                                   \
    __builtin_amdgcn_s_barrier();                                             \
    asm volatile("s_waitcnt lgkmcnt(0)" ::: "memory");                        \
    __builtin_amdgcn_sched_barrier(0);                                        \
    __builtin_amdgcn_s_setprio(1);                                            \
    MFMA_Q(3, a1f, b1f);                                                      \
    __builtin_amdgcn_s_setprio(0);                                            \
    __builtin_amdgcn_sched_barrier(0);                                        \
    if ((t) < NSTEP - 2) asm volatile("s_waitcnt vmcnt(6)" ::: "memory");     \
    else                 asm volatile("s_waitcnt vmcnt(0)" ::: "memory");     \
    __builtin_amdgcn_s_barrier();                                             \
  } while(0)

#define GEMM_PROLOGUE()                                                       \
    STG_A(0, 0, 0); STG_B(0, 0, 0); STG_A(0, 1, 0); STG_B(0, 1, 0);           \
    STG_A(1, 0, 1); STG_B(1, 0, 1); STG_A(1, 1, 1);                           \
    asm volatile("s_waitcnt vmcnt(6)" ::: "memory");                          \
    __builtin_amdgcn_s_barrier();

// ---------------- GEMM1: H = relu(Xg @ w1^T + b1), bf16 out ----------------
// grid (HSZ/256=16, NTOK/256=16, NEXP) = 2048 blocks, block 512
__global__ __launch_bounds__(512) void gemm1_bf_kernel(
    const unsigned short* __restrict__ Xbf, const unsigned short* __restrict__ W1bf,
    const float* __restrict__ b1, const int* __restrict__ cnt,
    const int* __restrict__ tokl, unsigned short* __restrict__ Hbuf) {
  // T1 swizzle: chunk = (wx, wz) sharing a 1MB W1 panel; all 16 wy-members
  // land on XCD = b%8. b -> (xcd, slot); chunk c = xcd + 8*(slot/16).
  const int b = blockIdx.x + 16 * blockIdx.y + 256 * blockIdx.z;  // 0..2047
  const int xcd = b & 7;
  const int slot = b >> 3;                 // 0..255
  const int c = xcd + 8 * (slot >> 4);     // 0..127 = wx + 16*wz
  const int wx = c & 15, wz = c >> 4, wy = slot & 15;

  const int e = wz;
  const int ne = cnt[e];
  const int m0 = wy * 256;
  if (m0 >= ne) return;
  const int n0 = wx * 256;
  int toff = 0;
  for (int i = 0; i < NEXP; ++i) toff += (i < e) ? cnt[i] : 0;

  __shared__ __align__(16) unsigned short SH[65536];  // 128 KB

  const int tid = threadIdx.x;
  const int lane = tid & 63;
  const int w = tid >> 6;       // 0..7
  const int aw = w >> 1;        // 0..3: 32-row strip within quadrant
  const int bw = w & 1;         // 0..1: 64-col strip within quadrant
  const int fr = lane & 15;
  const int cb0 = lane >> 4;    // 0..3

  constexpr int NSTEP = DMODEL / 64;  // 16
  const size_t Bstr = DMODEL;

  const int srow8 = lane >> 3;
  const int sswz = ((lane & 7) ^ srow8) * 8;
  const int* tlist = tokl + e * NTOK;
  const unsigned short* aP[2][2];
#pragma unroll
  for (int h = 0; h < 2; ++h)
#pragma unroll
    for (int cc = 0; cc < 2; ++cc) {
      int gr = m0 + h * 128 + w * 16 + cc * 8 + srow8;
      int tk = tlist[(gr < ne) ? gr : 0];
      aP[h][cc] = Xbf + (size_t)tk * DMODEL + sswz;
    }
  const unsigned short* bP = W1bf + (size_t)e * HSZ * DMODEL
      + (size_t)(n0 + w * 16 + srow8) * DMODEL + sswz;

  int aoff[2][2], boff[4][2];
#pragma unroll
  for (int i = 0; i < 2; ++i)
#pragma unroll
    for (int kk = 0; kk < 2; ++kk) {
      int rr = aw * 32 + i * 16 + fr;
      aoff[i][kk] = rr * 64 + (((kk * 4 + cb0) ^ (fr & 7)) * 8);
    }
#pragma unroll
  for (int j = 0; j < 4; ++j)
#pragma unroll
    for (int kk = 0; kk < 2; ++kk) {
      int rr = bw * 64 + j * 16 + fr;
      boff[j][kk] = rr * 64 + (((kk * 4 + cb0) ^ (fr & 7)) * 8);
    }

  f32x4 acc[4][2][4];
#pragma unroll
  for (int q = 0; q < 4; ++q)
#pragma unroll
    for (int i = 0; i < 2; ++i)
#pragma unroll
      for (int j = 0; j < 4; ++j) acc[q][i][j] = (f32x4){0.f, 0.f, 0.f, 0.f};

  bf16x8 a0f[2][2], a1f[2][2], b0f[4][2], b1f[4][2];

  GEMM_PROLOGUE()
  for (int t = 0; t < NSTEP; t += 2) {
    KTILE(0, t);
    KTILE(1, t + 1);
  }

  const int dq = cb0 * 4;
#pragma unroll
  for (int q = 0; q < 4; ++q) {
    const int qm = q >> 1, qn = q & 1;
#pragma unroll
    for (int i = 0; i < 2; ++i) {
      int trow = m0 + qm * 128 + aw * 32 + i * 16 + fr;
      if (trow >= ne) continue;
      size_t hrow = (size_t)(toff + trow) * HSZ;
#pragma unroll
      for (int j = 0; j < 4; ++j) {
        int hcol = n0 + qn * 128 + bw * 64 + j * 16 + dq;
        const float* bp = b1 + e * HSZ + hcol;
        unsigned short u[4];
#pragma unroll
        for (int r = 0; r < 4; ++r)
          u[r] = f2bf(fmaxf(acc[q][i][j][r] + bp[r], 0.f));
        *(ushort4*)&Hbuf[hrow + hcol] = make_ushort4(u[0], u[1], u[2], u[3]);
      }
    }
  }
}

// ---------------- GEMM2: split-K=2 partials, same 8-phase template ---------
// grid (DMODEL/256=4, NTOK/256=16, NEXP*KSPLIT) = 1024 blocks, block 512
__global__ __launch_bounds__(512) void gemm2_bf_kernel(
    const unsigned short* __restrict__ Hbuf, const unsigned short* __restrict__ W2bf,
    const int* __restrict__ cnt, const float* __restrict__ twgt,
    float* __restrict__ Ybuf) {
  // T1 swizzle: chunk = (wx, wz) sharing a 1MB W2 panel.
  const int b = blockIdx.x + 4 * blockIdx.y + 64 * blockIdx.z;  // 0..1023
  const int xcd = b & 7;
  const int slot = b >> 3;                 // 0..127
  const int c = xcd + 8 * (slot >> 4);     // 0..63 = wx + 4*wz
  const int wx = c & 3, wz = c >> 2, wy = slot & 15;

  const int e = wz & 7;
  const int ks = wz >> 3;
  const int ne = cnt[e];
  const int m0 = wy * 256;
  if (m0 >= ne) return;
  const int n0 = wx * 256;
  const int kbase = ks * (HSZ / KSPLIT);
  int toff = 0;
  for (int i = 0; i < NEXP; ++i) toff += (i < e) ? cnt[i] : 0;

  __shared__ __align__(16) unsigned short SH[65536];  // 128 KB

  const int tid = threadIdx.x;
  const int lane = tid & 63;
  const int w = tid >> 6;
  const int aw = w >> 1;
  const int bw = w & 1;
  const int fr = lane & 15;
  const int cb0 = lane >> 4;

  constexpr int NSTEP = (HSZ / KSPLIT) / 64;  // 32
  const size_t Bstr = HSZ;

  const int srow8 = lane >> 3;
  const int sswz = ((lane & 7) ^ srow8) * 8;
  const unsigned short* aP[2][2];
#pragma unroll
  for (int h = 0; h < 2; ++h)
#pragma unroll
    for (int cc = 0; cc < 2; ++cc) {
      int gr = m0 + h * 128 + w * 16 + cc * 8 + srow8;
      int rc = (gr < ne) ? gr : 0;
      aP[h][cc] = Hbuf + (size_t)(toff + rc) * HSZ + kbase + sswz;
    }
  const unsigned short* bP = W2bf + (size_t)e * DMODEL * HSZ
      + (size_t)(n0 + w * 16 + srow8) * HSZ + kbase + sswz;

  int aoff[2][2], boff[4][2];
#pragma unroll
  for (int i = 0; i < 2; ++i)
#pragma unroll
    for (int kk = 0; kk < 2; ++kk) {
      int rr = aw * 32 + i * 16 + fr;
      aoff[i][kk] = rr * 64 + (((kk * 4 + cb0) ^ (fr & 7)) * 8);
    }
#pragma unroll
  for (int j = 0; j < 4; ++j)
#pragma unroll
    for (int kk = 0; kk < 2; ++kk) {
      int rr = bw * 64 + j * 16 + fr;
      boff[j][kk] = rr * 64 + (((kk * 4 + cb0) ^ (fr & 7)) * 8);
    }

  f32x4 acc[4][2][4];
#pragma unroll
  for (int q = 0; q < 4; ++q)
#pragma unroll
    for (int i = 0; i < 2; ++i)
#pragma unroll
      for (int j = 0; j < 4; ++j) acc[q][i][j] = (f32x4){0.f, 0.f, 0.f, 0.f};

  bf16x8 a0f[2][2], a1f[2][2], b0f[4][2], b1f[4][2];

  GEMM_PROLOGUE()
  for (int t = 0; t < NSTEP; t += 2) {
    KTILE(0, t);
    KTILE(1, t + 1);
  }

  const float* wlist = twgt + e * NTOK;
  float* yp = Ybuf + (size_t)ks * (2 * NTOK) * DMODEL;
  const int dq = cb0 * 4;
#pragma unroll
  for (int q = 0; q < 4; ++q) {
    const int qm = q >> 1, qn = q & 1;
#pragma unroll
    for (int i = 0; i < 2; ++i) {
      int trow = m0 + qm * 128 + aw * 32 + i * 16 + fr;
      if (trow >= ne) continue;
      float wgt = wlist[trow];
      float* yrow = yp + (size_t)(toff + trow) * DMODEL;
#pragma unroll
      for (int j = 0; j < 4; ++j) {
        int d0 = n0 + qn * 128 + bw * 64 + j * 16 + dq;
        float4 v = make_float4(wgt * acc[q][i][j][0], wgt * acc[q][i][j][1],
                               wgt * acc[q][i][j][2], wgt * acc[q][i][j][3]);
        *(float4*)(yrow + d0) = v;
      }
    }
  }
}

// ---------------- combine: out[t] = sum of 2 routes x KSPLIT partials + w*b2
__global__ __launch_bounds__(256) void combine_kernel(
    const float* __restrict__ Ybuf, const float* __restrict__ b2,
    const int* __restrict__ cnt, const int* __restrict__ sidx,
    const float* __restrict__ twgt, float* __restrict__ out) {
  int t = blockIdx.x;
  int offv[NEXP];
  int s = 0;
#pragma unroll
  for (int e = 0; e < NEXP; ++e) { offv[e] = s; s += cnt[e]; }
  int s0 = sidx[2 * t], s1 = sidx[2 * t + 1];
  int e0 = s0 >> 16, e1 = s1 >> 16;
  int sl0 = s0 & 0xffff, sl1 = s1 & 0xffff;
  size_t r0 = (size_t)(offv[e0] + sl0) * DMODEL;
  size_t r1 = (size_t)(offv[e1] + sl1) * DMODEL;
  float w0 = twgt[e0 * NTOK + sl0];
  float w1 = twgt[e1 * NTOK + sl1];
  const size_t PSTR = (size_t)(2 * NTOK) * DMODEL;
  int c = threadIdx.x * 4;
  float4 a0 = *(const float4*)(Ybuf + r0 + c);
  float4 a1 = *(const float4*)(Ybuf + PSTR + r0 + c);
  float4 c0 = *(const float4*)(Ybuf + r1 + c);
  float4 c1 = *(const float4*)(Ybuf + PSTR + r1 + c);
  float4 bb0 = *(const float4*)(b2 + (size_t)e0 * DMODEL + c);
  float4 bb1 = *(const float4*)(b2 + (size_t)e1 * DMODEL + c);
  *(float4*)(out + (size_t)t * DMODEL + c) = make_float4(
      a0.x + a1.x + c0.x + c1.x + w0 * bb0.x + w1 * bb1.x,
      a0.y + a1.y + c0.y + c1.y + w0 * bb0.y + w1 * bb1.y,
      a0.z + a1.z + c0.z + c1.z + w0 * bb0.z + w1 * bb1.z,
      a0.w + a1.w + c0.w + c1.w + w0 * bb0.w + w1 * bb1.w);
}

extern "C" void kernel_launch(void* const* d_in, const int* in_sizes, int n_in,
                              void* d_out, int out_size, void* d_ws, size_t ws_size,
                              hipStream_t stream) {
  const float* x  = (const float*)d_in[0];
  const float* gw = (const float*)d_in[1];
  const float* w1 = (const float*)d_in[2];
  const float* b1 = (const float*)d_in[3];
  const float* w2 = (const float*)d_in[4];
  const float* b2 = (const float*)d_in[5];
  float* out = (float*)d_out;

  char* ws = (char*)d_ws;
  int* cnt    = (int*)ws;                                  // 32 B
  int* tokl   = (int*)(ws + 128);                          // 128 KB
  float* twgt = (float*)(ws + 128 + NEXP * NTOK * 4);      // 128 KB
  int* sidx   = (int*)(ws + 128 + 2 * NEXP * NTOK * 4);    // 32 KB

  constexpr size_t OFF_XBF  = 327680;                                      // 320 KB
  constexpr size_t OFF_W1BF = OFF_XBF  + (size_t)NTOK * DMODEL * 2;        // +8 MB
  constexpr size_t OFF_W2BF = OFF_W1BF + (size_t)NEXP * HSZ * DMODEL * 2;  // +64 MB
  constexpr size_t OFF_HBUF = OFF_W2BF + (size_t)NEXP * DMODEL * HSZ * 2;  // +64 MB
  unsigned short* Xbf  = (unsigned short*)(ws + OFF_XBF);
  unsigned short* W1bf = (unsigned short*)(ws + OFF_W1BF);
  unsigned short* W2bf = (unsigned short*)(ws + OFF_W2BF);
  unsigned short* Hbuf = (unsigned short*)(ws + OFF_HBUF);
  // Y partials (2 x 32MB) overlay W1bf (64MB, dead after gemm1)
  float* Ybuf = (float*)(ws + OFF_W1BF);

  hipMemsetAsync(cnt, 0, 32, stream);
  router_kernel<<<NTOK / 16, 256, 0, stream>>>(x, gw, cnt, tokl, twgt, sidx, Xbf);
  const size_t ncvt = 2 * (size_t)NEXP * HSZ * DMODEL / 4;
  cvt_all_kernel<<<(unsigned)((ncvt + 255) / 256), 256, 0, stream>>>(
      w1, w2, W1bf, W2bf);
  gemm1_bf_kernel<<<dim3(HSZ / 256, NTOK / 256, NEXP), 512, 0, stream>>>(
      Xbf, W1bf, b1, cnt, tokl, Hbuf);
  gemm2_bf_kernel<<<dim3(DMODEL / 256, NTOK / 256, NEXP * KSPLIT), 512, 0, stream>>>(
      Hbuf, W2bf, cnt, twgt, Ybuf);
  combine_kernel<<<NTOK, 256, 0, stream>>>(Ybuf, b2, cnt, sidx, twgt, out);
}

// Round 6
// 551.483 us; speedup vs baseline: 1.0515x; 1.0515x over previous
//
#include <hip/hip_runtime.h>
#include <hip/hip_bf16.h>
#include <stdint.h>

#define DMODEL 1024
#define NEXP   8
#define HSZ    4096
#define NTOK   4096   // B*S
#define KSPLIT 2      // gemm2 split-K factor

typedef __attribute__((ext_vector_type(8))) short bf16x8;
typedef __attribute__((ext_vector_type(4))) float f32x4;

// fp32 -> bf16 round-to-nearest
__device__ __forceinline__ unsigned short f2bf(float f) {
  union { float f; unsigned u; } v; v.f = f;
  return (unsigned short)((v.u + 0x8000u) >> 16);
}

// async 16B/lane global->LDS DMA. Per-lane global addr; LDS dest wave-uniform,
// HW scatters lane l -> lds + l*16.
__device__ __forceinline__ void gl2lds16(const void* g, void* lds) {
  __builtin_amdgcn_global_load_lds(
      (const __attribute__((address_space(1))) unsigned*)g,
      (__attribute__((address_space(3))) unsigned*)lds, 16, 0, 0);
}

// ---------------- fused fp32 -> bf16 bulk convert (w1, w2) -----------------
__global__ __launch_bounds__(256) void cvt_all_kernel(
    const float* __restrict__ w1, const float* __restrict__ w2,
    unsigned short* __restrict__ w1b, unsigned short* __restrict__ w2b) {
  const size_t n1 = (size_t)NEXP * HSZ * DMODEL / 4;
  size_t i = (size_t)blockIdx.x * 256 + threadIdx.x;
  const float* src; unsigned short* dst; size_t j;
  if (i < n1) { src = w1; dst = w1b; j = i; }
  else        { src = w2; dst = w2b; j = i - n1; }
  float4 v = ((const float4*)src)[j];
  ((ushort4*)dst)[j] = make_ushort4(f2bf(v.x), f2bf(v.y), f2bf(v.z), f2bf(v.w));
}

// ---------------- router: 256 blocks x 16 tokens, batched atomics ----------
// float4-vectorized x loads + gw loads + ushort4 bf16 stores (G13).
__global__ __launch_bounds__(256) void router_kernel(
    const float* __restrict__ x, const float* __restrict__ gw,
    int* __restrict__ cnt, int* __restrict__ tokl, float* __restrict__ twgt,
    int* __restrict__ sidx, unsigned short* __restrict__ xb) {
  __shared__ int lcnt[NEXP];
  __shared__ int lbase[NEXP];
  __shared__ int rE[32];
  __shared__ int rS[32];
  __shared__ float rW[32];
  const int tid = threadIdx.x;
  const int wave = tid >> 6;
  const int lane = tid & 63;
  if (tid < NEXP) lcnt[tid] = 0;
  __syncthreads();

  for (int i = 0; i < 4; ++i) {
    int lt = wave * 4 + i;
    int t = blockIdx.x * 16 + lt;
    const float4* xr = (const float4*)(x + (size_t)t * DMODEL);
    ushort4* xbr = (ushort4*)(xb + (size_t)t * DMODEL);
    float acc[NEXP];
#pragma unroll
    for (int e = 0; e < NEXP; ++e) acc[e] = 0.f;
#pragma unroll
    for (int d4 = 0; d4 < DMODEL / 4 / 64; ++d4) {
      int idx = d4 * 64 + lane;
      float4 xv = xr[idx];
      xbr[idx] = make_ushort4(f2bf(xv.x), f2bf(xv.y), f2bf(xv.z), f2bf(xv.w));
#pragma unroll
      for (int e = 0; e < NEXP; ++e) {
        float4 gv = ((const float4*)(gw + e * DMODEL))[idx];
        acc[e] = fmaf(xv.x, gv.x, acc[e]);
        acc[e] = fmaf(xv.y, gv.y, acc[e]);
        acc[e] = fmaf(xv.z, gv.z, acc[e]);
        acc[e] = fmaf(xv.w, gv.w, acc[e]);
      }
    }
#pragma unroll
    for (int e = 0; e < NEXP; ++e) {
#pragma unroll
      for (int o = 32; o > 0; o >>= 1) acc[e] += __shfl_down(acc[e], o);
    }
    if (lane == 0) {
      float m = acc[0];
#pragma unroll
      for (int e = 1; e < NEXP; ++e) m = fmaxf(m, acc[e]);
      float p[NEXP]; float s = 0.f;
#pragma unroll
      for (int e = 0; e < NEXP; ++e) { p[e] = __expf(acc[e] - m); s += p[e]; }
      float inv = 1.f / s;
      int i0 = 0; float b0 = p[0];
#pragma unroll
      for (int e = 1; e < NEXP; ++e) if (p[e] > b0) { b0 = p[e]; i0 = e; }
      int i1 = (i0 == 0) ? 1 : 0; float b1v = p[i1];
#pragma unroll
      for (int e = 0; e < NEXP; ++e) if (e != i0 && p[e] > b1v) { b1v = p[e]; i1 = e; }
      int s0l = atomicAdd(&lcnt[i0], 1);
      rE[lt * 2] = i0; rS[lt * 2] = s0l; rW[lt * 2] = b0 * inv;
      int s1l = atomicAdd(&lcnt[i1], 1);
      rE[lt * 2 + 1] = i1; rS[lt * 2 + 1] = s1l; rW[lt * 2 + 1] = b1v * inv;
    }
  }
  __syncthreads();
  if (tid < NEXP) lbase[tid] = atomicAdd(&cnt[tid], lcnt[tid]);
  __syncthreads();
  if (tid < 32) {
    int e = rE[tid];
    int p = lbase[e] + rS[tid];
    int t = blockIdx.x * 16 + (tid >> 1);
    tokl[e * NTOK + p] = t;
    twgt[e * NTOK + p] = rW[tid];
    sidx[2 * t + (tid & 1)] = (e << 16) | p;
  }
}

// ===================== 256x256 / BK=64 / 8-wave pipeline ====================
// R6 change: ONE barrier per phase (was 2) + all tile ds_reads issued early
// (A0,B0,B1 in PH0; A1 in PH1). Compiler's counted lgkmcnt leaves b1f/a1f in
// flight under MFMA0/1 -> LDS drain overlaps the matrix pipe (was serial).
// Hazard invariant preserved: each STG(region) issues >=1 barrier after that
// region's last ds_read completes (reads complete before the MFMA that uses
// them, which precedes the wave's barrier arrival):
//   STG_B(buf^1,B1,t+1) PH0: B1(t-1) reads done before boundary bar.
//   STG_A(buf,A0,t+2)  PH1: a0f reads done before MFMA0 < BAR0.
//   STG_B(buf,B0,t+2)  PH2: b0f reads done before MFMA0 < BAR0 < BAR1.
//   STG_A(buf,A1,t+2)  PH3: a1f reads done before MFMA2 < BAR2.
// Boundary vmcnt(6) schedule unchanged from R4 (certifies tile t+1 exactly).

#define SOFF(buf, mat, half) (((buf) * 4 + (mat) * 2 + (half)) * 8192)

#define STG_A(buf, half, kt) do { if ((kt) < NSTEP) {                         \
    gl2lds16(aP[half][0] + (size_t)(kt) * 64, &SH[SOFF(buf,0,half) + (w*16)*64]);     \
    gl2lds16(aP[half][1] + (size_t)(kt) * 64, &SH[SOFF(buf,0,half) + (w*16+8)*64]); } } while(0)

#define STG_B(buf, half, kt) do { if ((kt) < NSTEP) {                         \
    gl2lds16(bP + (size_t)((half)*128) * Bstr + (size_t)(kt) * 64, &SH[SOFF(buf,1,half) + (w*16)*64]);   \
    gl2lds16(bP + (size_t)((half)*128+8) * Bstr + (size_t)(kt) * 64, &SH[SOFF(buf,1,half) + (w*16+8)*64]); } } while(0)

#define RD_A(dst, buf, half) do {                                             \
    dst[0][0] = *(const bf16x8*)&SH[SOFF(buf,0,half) + aoff[0][0]];           \
    dst[0][1] = *(const bf16x8*)&SH[SOFF(buf,0,half) + aoff[0][1]];           \
    dst[1][0] = *(const bf16x8*)&SH[SOFF(buf,0,half) + aoff[1][0]];           \
    dst[1][1] = *(const bf16x8*)&SH[SOFF(buf,0,half) + aoff[1][1]]; } while(0)

#define RD_B(dst, buf, half) do {                                             \
    _Pragma("unroll") for (int j_ = 0; j_ < 4; ++j_) {                        \
      dst[j_][0] = *(const bf16x8*)&SH[SOFF(buf,1,half) + boff[j_][0]];       \
      dst[j_][1] = *(const bf16x8*)&SH[SOFF(buf,1,half) + boff[j_][1]]; } } while(0)

#define MFMA_Q(q, a, b) do {                                                  \
    _Pragma("unroll") for (int i_ = 0; i_ < 2; ++i_)                          \
    _Pragma("unroll") for (int j_ = 0; j_ < 4; ++j_)                          \
    _Pragma("unroll") for (int k_ = 0; k_ < 2; ++k_)                          \
      acc[q][i_][j_] = __builtin_amdgcn_mfma_f32_16x16x32_bf16(               \
          b[j_][k_], a[i_][k_], acc[q][i_][j_], 0, 0, 0); } while(0)

#define MFMA_PRIO(q, a, b)                                                    \
    __builtin_amdgcn_s_setprio(1);                                            \
    MFMA_Q(q, a, b);                                                          \
    __builtin_amdgcn_s_setprio(0);

// raw s_barrier bracketed by compiler memory fences (no machine insts) so
// LDS/staging ops can't be IR-hoisted across it (rule-18 family).
#define BAR() do { asm volatile("" ::: "memory");                             \
    __builtin_amdgcn_s_barrier(); asm volatile("" ::: "memory"); } while(0)

#define KTILE(buf, t) do {                                                    \
    RD_A(a0f, buf, 0); RD_B(b0f, buf, 0); RD_B(b1f, buf, 1);                  \
    STG_B(buf ^ 1, 1, (t) + 1);                                               \
    MFMA_PRIO(0, a0f, b0f)                                                    \
    BAR();                                                                    \
    RD_A(a1f, buf, 1);                                                        \
    STG_A(buf, 0, (t) + 2);                                                   \
    MFMA_PRIO(1, a0f, b1f)                                                    \
    BAR();                                                                    \
    STG_B(buf, 0, (t) + 2);                                                   \
    MFMA_PRIO(2, a1f, b0f)                                                    \
    BAR();                                                                    \
    STG_A(buf, 1, (t) + 2);                                                   \
    MFMA_PRIO(3, a1f, b1f)                                                    \
    if ((t) < NSTEP - 2) asm volatile("s_waitcnt vmcnt(6)" ::: "memory");     \
    else                 asm volatile("s_waitcnt vmcnt(0)" ::: "memory");     \
    BAR();                                                                    \
  } while(0)

#define GEMM_PROLOGUE()                                                       \
    STG_A(0, 0, 0); STG_B(0, 0, 0); STG_A(0, 1, 0); STG_B(0, 1, 0);           \
    STG_A(1, 0, 1); STG_B(1, 0, 1); STG_A(1, 1, 1);                           \
    asm volatile("s_waitcnt vmcnt(6)" ::: "memory");                          \
    __builtin_amdgcn_s_barrier();

// ---------------- GEMM1: H = relu(Xg @ w1^T + b1), bf16 out ----------------
// grid (HSZ/256=16, NTOK/256=16, NEXP) = 2048 blocks, block 512
__global__ __launch_bounds__(512) void gemm1_bf_kernel(
    const unsigned short* __restrict__ Xbf, const unsigned short* __restrict__ W1bf,
    const float* __restrict__ b1, const int* __restrict__ cnt,
    const int* __restrict__ tokl, unsigned short* __restrict__ Hbuf) {
  // T1 swizzle: chunk = (wx, wz) sharing a 1MB W1 panel; all 16 wy-members
  // land on XCD = b%8. b -> (xcd, slot); chunk c = xcd + 8*(slot/16).
  const int b = blockIdx.x + 16 * blockIdx.y + 256 * blockIdx.z;  // 0..2047
  const int xcd = b & 7;
  const int slot = b >> 3;                 // 0..255
  const int c = xcd + 8 * (slot >> 4);     // 0..127 = wx + 16*wz
  const int wx = c & 15, wz = c >> 4, wy = slot & 15;

  const int e = wz;
  const int ne = cnt[e];
  const int m0 = wy * 256;
  if (m0 >= ne) return;
  const int n0 = wx * 256;
  int toff = 0;
  for (int i = 0; i < NEXP; ++i) toff += (i < e) ? cnt[i] : 0;

  __shared__ __align__(16) unsigned short SH[65536];  // 128 KB

  const int tid = threadIdx.x;
  const int lane = tid & 63;
  const int w = tid >> 6;       // 0..7
  const int aw = w >> 1;        // 0..3: 32-row strip within quadrant
  const int bw = w & 1;         // 0..1: 64-col strip within quadrant
  const int fr = lane & 15;
  const int cb0 = lane >> 4;    // 0..3

  constexpr int NSTEP = DMODEL / 64;  // 16
  const size_t Bstr = DMODEL;

  const int srow8 = lane >> 3;
  const int sswz = ((lane & 7) ^ srow8) * 8;
  const int* tlist = tokl + e * NTOK;
  const unsigned short* aP[2][2];
#pragma unroll
  for (int h = 0; h < 2; ++h)
#pragma unroll
    for (int cc = 0; cc < 2; ++cc) {
      int gr = m0 + h * 128 + w * 16 + cc * 8 + srow8;
      int tk = tlist[(gr < ne) ? gr : 0];
      aP[h][cc] = Xbf + (size_t)tk * DMODEL + sswz;
    }
  const unsigned short* bP = W1bf + (size_t)e * HSZ * DMODEL
      + (size_t)(n0 + w * 16 + srow8) * DMODEL + sswz;

  int aoff[2][2], boff[4][2];
#pragma unroll
  for (int i = 0; i < 2; ++i)
#pragma unroll
    for (int kk = 0; kk < 2; ++kk) {
      int rr = aw * 32 + i * 16 + fr;
      aoff[i][kk] = rr * 64 + (((kk * 4 + cb0) ^ (fr & 7)) * 8);
    }
#pragma unroll
  for (int j = 0; j < 4; ++j)
#pragma unroll
    for (int kk = 0; kk < 2; ++kk) {
      int rr = bw * 64 + j * 16 + fr;
      boff[j][kk] = rr * 64 + (((kk * 4 + cb0) ^ (fr & 7)) * 8);
    }

  f32x4 acc[4][2][4];
#pragma unroll
  for (int q = 0; q < 4; ++q)
#pragma unroll
    for (int i = 0; i < 2; ++i)
#pragma unroll
      for (int j = 0; j < 4; ++j) acc[q][i][j] = (f32x4){0.f, 0.f, 0.f, 0.f};

  bf16x8 a0f[2][2], a1f[2][2], b0f[4][2], b1f[4][2];

  GEMM_PROLOGUE()
  for (int t = 0; t < NSTEP; t += 2) {
    KTILE(0, t);
    KTILE(1, t + 1);
  }

  const int dq = cb0 * 4;
#pragma unroll
  for (int q = 0; q < 4; ++q) {
    const int qm = q >> 1, qn = q & 1;
#pragma unroll
    for (int i = 0; i < 2; ++i) {
      int trow = m0 + qm * 128 + aw * 32 + i * 16 + fr;
      if (trow >= ne) continue;
      size_t hrow = (size_t)(toff + trow) * HSZ;
#pragma unroll
      for (int j = 0; j < 4; ++j) {
        int hcol = n0 + qn * 128 + bw * 64 + j * 16 + dq;
        const float* bp = b1 + e * HSZ + hcol;
        unsigned short u[4];
#pragma unroll
        for (int r = 0; r < 4; ++r)
          u[r] = f2bf(fmaxf(acc[q][i][j][r] + bp[r], 0.f));
        *(ushort4*)&Hbuf[hrow + hcol] = make_ushort4(u[0], u[1], u[2], u[3]);
      }
    }
  }
}

// ---------------- GEMM2: split-K=2 partials, same pipeline -----------------
// grid (DMODEL/256=4, NTOK/256=16, NEXP*KSPLIT) = 1024 blocks, block 512
__global__ __launch_bounds__(512) void gemm2_bf_kernel(
    const unsigned short* __restrict__ Hbuf, const unsigned short* __restrict__ W2bf,
    const int* __restrict__ cnt, const float* __restrict__ twgt,
    float* __restrict__ Ybuf) {
  // T1 swizzle: chunk = (wx, wz) sharing a 1MB W2 panel.
  const int b = blockIdx.x + 4 * blockIdx.y + 64 * blockIdx.z;  // 0..1023
  const int xcd = b & 7;
  const int slot = b >> 3;                 // 0..127
  const int c = xcd + 8 * (slot >> 4);     // 0..63 = wx + 4*wz
  const int wx = c & 3, wz = c >> 2, wy = slot & 15;

  const int e = wz & 7;
  const int ks = wz >> 3;
  const int ne = cnt[e];
  const int m0 = wy * 256;
  if (m0 >= ne) return;
  const int n0 = wx * 256;
  const int kbase = ks * (HSZ / KSPLIT);
  int toff = 0;
  for (int i = 0; i < NEXP; ++i) toff += (i < e) ? cnt[i] : 0;

  __shared__ __align__(16) unsigned short SH[65536];  // 128 KB

  const int tid = threadIdx.x;
  const int lane = tid & 63;
  const int w = tid >> 6;
  const int aw = w >> 1;
  const int bw = w & 1;
  const int fr = lane & 15;
  const int cb0 = lane >> 4;

  constexpr int NSTEP = (HSZ / KSPLIT) / 64;  // 32
  const size_t Bstr = HSZ;

  const int srow8 = lane >> 3;
  const int sswz = ((lane & 7) ^ srow8) * 8;
  const unsigned short* aP[2][2];
#pragma unroll
  for (int h = 0; h < 2; ++h)
#pragma unroll
    for (int cc = 0; cc < 2; ++cc) {
      int gr = m0 + h * 128 + w * 16 + cc * 8 + srow8;
      int rc = (gr < ne) ? gr : 0;
      aP[h][cc] = Hbuf + (size_t)(toff + rc) * HSZ + kbase + sswz;
    }
  const unsigned short* bP = W2bf + (size_t)e * DMODEL * HSZ
      + (size_t)(n0 + w * 16 + srow8) * HSZ + kbase + sswz;

  int aoff[2][2], boff[4][2];
#pragma unroll
  for (int i = 0; i < 2; ++i)
#pragma unroll
    for (int kk = 0; kk < 2; ++kk) {
      int rr = aw * 32 + i * 16 + fr;
      aoff[i][kk] = rr * 64 + (((kk * 4 + cb0) ^ (fr & 7)) * 8);
    }
#pragma unroll
  for (int j = 0; j < 4; ++j)
#pragma unroll
    for (int kk = 0; kk < 2; ++kk) {
      int rr = bw * 64 + j * 16 + fr;
      boff[j][kk] = rr * 64 + (((kk * 4 + cb0) ^ (fr & 7)) * 8);
    }

  f32x4 acc[4][2][4];
#pragma unroll
  for (int q = 0; q < 4; ++q)
#pragma unroll
    for (int i = 0; i < 2; ++i)
#pragma unroll
      for (int j = 0; j < 4; ++j) acc[q][i][j] = (f32x4){0.f, 0.f, 0.f, 0.f};

  bf16x8 a0f[2][2], a1f[2][2], b0f[4][2], b1f[4][2];

  GEMM_PROLOGUE()
  for (int t = 0; t < NSTEP; t += 2) {
    KTILE(0, t);
    KTILE(1, t + 1);
  }

  const float* wlist = twgt + e * NTOK;
  float* yp = Ybuf + (size_t)ks * (2 * NTOK) * DMODEL;
  const int dq = cb0 * 4;
#pragma unroll
  for (int q = 0; q < 4; ++q) {
    const int qm = q >> 1, qn = q & 1;
#pragma unroll
    for (int i = 0; i < 2; ++i) {
      int trow = m0 + qm * 128 + aw * 32 + i * 16 + fr;
      if (trow >= ne) continue;
      float wgt = wlist[trow];
      float* yrow = yp + (size_t)(toff + trow) * DMODEL;
#pragma unroll
      for (int j = 0; j < 4; ++j) {
        int d0 = n0 + qn * 128 + bw * 64 + j * 16 + dq;
        float4 v = make_float4(wgt * acc[q][i][j][0], wgt * acc[q][i][j][1],
                               wgt * acc[q][i][j][2], wgt * acc[q][i][j][3]);
        *(float4*)(yrow + d0) = v;
      }
    }
  }
}

// ---------------- combine: out[t] = sum of 2 routes x KSPLIT partials + w*b2
__global__ __launch_bounds__(256) void combine_kernel(
    const float* __restrict__ Ybuf, const float* __restrict__ b2,
    const int* __restrict__ cnt, const int* __restrict__ sidx,
    const float* __restrict__ twgt, float* __restrict__ out) {
  int t = blockIdx.x;
  int offv[NEXP];
  int s = 0;
#pragma unroll
  for (int e = 0; e < NEXP; ++e) { offv[e] = s; s += cnt[e]; }
  int s0 = sidx[2 * t], s1 = sidx[2 * t + 1];
  int e0 = s0 >> 16, e1 = s1 >> 16;
  int sl0 = s0 & 0xffff, sl1 = s1 & 0xffff;
  size_t r0 = (size_t)(offv[e0] + sl0) * DMODEL;
  size_t r1 = (size_t)(offv[e1] + sl1) * DMODEL;
  float w0 = twgt[e0 * NTOK + sl0];
  float w1 = twgt[e1 * NTOK + sl1];
  const size_t PSTR = (size_t)(2 * NTOK) * DMODEL;
  int c = threadIdx.x * 4;
  float4 a0 = *(const float4*)(Ybuf + r0 + c);
  float4 a1 = *(const float4*)(Ybuf + PSTR + r0 + c);
  float4 c0 = *(const float4*)(Ybuf + r1 + c);
  float4 c1 = *(const float4*)(Ybuf + PSTR + r1 + c);
  float4 bb0 = *(const float4*)(b2 + (size_t)e0 * DMODEL + c);
  float4 bb1 = *(const float4*)(b2 + (size_t)e1 * DMODEL + c);
  *(float4*)(out + (size_t)t * DMODEL + c) = make_float4(
      a0.x + a1.x + c0.x + c1.x + w0 * bb0.x + w1 * bb1.x,
      a0.y + a1.y + c0.y + c1.y + w0 * bb0.y + w1 * bb1.y,
      a0.z + a1.z + c0.z + c1.z + w0 * bb0.z + w1 * bb1.z,
      a0.w + a1.w + c0.w + c1.w + w0 * bb0.w + w1 * bb1.w);
}

extern "C" void kernel_launch(void* const* d_in, const int* in_sizes, int n_in,
                              void* d_out, int out_size, void* d_ws, size_t ws_size,
                              hipStream_t stream) {
  const float* x  = (const float*)d_in[0];
  const float* gw = (const float*)d_in[1];
  const float* w1 = (const float*)d_in[2];
  const float* b1 = (const float*)d_in[3];
  const float* w2 = (const float*)d_in[4];
  const float* b2 = (const float*)d_in[5];
  float* out = (float*)d_out;

  char* ws = (char*)d_ws;
  int* cnt    = (int*)ws;                                  // 32 B
  int* tokl   = (int*)(ws + 128);                          // 128 KB
  float* twgt = (float*)(ws + 128 + NEXP * NTOK * 4);      // 128 KB
  int* sidx   = (int*)(ws + 128 + 2 * NEXP * NTOK * 4);    // 32 KB

  constexpr size_t OFF_XBF  = 327680;                                      // 320 KB
  constexpr size_t OFF_W1BF = OFF_XBF  + (size_t)NTOK * DMODEL * 2;        // +8 MB
  constexpr size_t OFF_W2BF = OFF_W1BF + (size_t)NEXP * HSZ * DMODEL * 2;  // +64 MB
  constexpr size_t OFF_HBUF = OFF_W2BF + (size_t)NEXP * DMODEL * HSZ * 2;  // +64 MB
  unsigned short* Xbf  = (unsigned short*)(ws + OFF_XBF);
  unsigned short* W1bf = (unsigned short*)(ws + OFF_W1BF);
  unsigned short* W2bf = (unsigned short*)(ws + OFF_W2BF);
  unsigned short* Hbuf = (unsigned short*)(ws + OFF_HBUF);
  // Y partials (2 x 32MB) overlay W1bf (64MB, dead after gemm1)
  float* Ybuf = (float*)(ws + OFF_W1BF);

  hipMemsetAsync(cnt, 0, 32, stream);
  router_kernel<<<NTOK / 16, 256, 0, stream>>>(x, gw, cnt, tokl, twgt, sidx, Xbf);
  const size_t ncvt = 2 * (size_t)NEXP * HSZ * DMODEL / 4;
  cvt_all_kernel<<<(unsigned)((ncvt + 255) / 256), 256, 0, stream>>>(
      w1, w2, W1bf, W2bf);
  gemm1_bf_kernel<<<dim3(HSZ / 256, NTOK / 256, NEXP), 512, 0, stream>>>(
      Xbf, W1bf, b1, cnt, tokl, Hbuf);
  gemm2_bf_kernel<<<dim3(DMODEL / 256, NTOK / 256, NEXP * KSPLIT), 512, 0, stream>>>(
      Hbuf, W2bf, cnt, twgt, Ybuf);
  combine_kernel<<<NTOK, 256, 0, stream>>>(Ybuf, b2, cnt, sidx, twgt, out);
}